// Round 1
// baseline (761.221 us; speedup 1.0000x reference)
//
#include <hip/hip_runtime.h>
#include <math.h>

// Problem dims (fixed by reference):
// B=8, N=4096, S=512, C=16, D=1024, E=256, H=1024, V=100000
// Outputs concatenated in d_out (float32):
//   [0]                : loss (scalar)
//   [1 .. 65536]       : scores (B,S,C) = 8*512*16
//   [65537 .. 69632]   : predictions (B,S) as float
#define BM 128
#define BN 128
#define BK 16
#define PAD 4

// ---------------------------------------------------------------------------
// Prep: gather candidate entity ids through linker_indices.
// cand_ids[pair*16 + c] = candidates_all[b, linker[b,s], c],  pair = b*512+s
// ---------------------------------------------------------------------------
__global__ __launch_bounds__(256) void k_prep(const int* __restrict__ linker,
                                              const int* __restrict__ cand_all,
                                              int* __restrict__ cand_ids) {
  int g = blockIdx.x * 256 + threadIdx.x;   // [0, 65536)
  int pair = g >> 4;
  int c = g & 15;
  int b = pair >> 9;
  int i = linker[pair];                     // linker is (B,S) flat == pair idx
  cand_ids[g] = cand_all[(((size_t)b << 12) + (size_t)i) * 16 + c];
}

// ---------------------------------------------------------------------------
// GEMM1: Hs[4096,1024] = gather(span_vecs, linker) @ W1[:D]
// 128x128 tile, BK=16, 8x8 microtile, 256 threads.
// ---------------------------------------------------------------------------
__global__ __launch_bounds__(256) void k_hs(const float* __restrict__ span,
                                            const float* __restrict__ W1,
                                            const int* __restrict__ linker,
                                            float* __restrict__ Hs) {
  const int tid = threadIdx.x;
  const int tx = tid & 15, ty = tid >> 4;
  const int row0 = blockIdx.y * BM;  // grid.y = 32
  const int col0 = blockIdx.x * BN;  // grid.x = 8

  __shared__ float As[BK][BM + PAD];
  __shared__ float Bs[BK][BN + PAD];
  __shared__ int rows_g[BM];

  if (tid < BM) {
    int m = row0 + tid;
    int b = m >> 9;
    rows_g[tid] = (b << 12) + linker[m];   // row into span_vecs (B*N rows)
  }
  __syncthreads();

  float acc[8][8] = {};

  for (int k0 = 0; k0 < 1024; k0 += BK) {
    // stage A (gathered rows), 512 float4s by 256 threads
#pragma unroll
    for (int l = 0; l < 2; ++l) {
      int f = tid + l * 256;
      int r = f >> 2;               // 0..127
      int kk = (f & 3) << 2;        // 0,4,8,12
      const float4 v =
          *(const float4*)(span + (size_t)rows_g[r] * 1024 + k0 + kk);
      As[kk + 0][r] = v.x;
      As[kk + 1][r] = v.y;
      As[kk + 2][r] = v.z;
      As[kk + 3][r] = v.w;
    }
    // stage B (W1s tile), coalesced
#pragma unroll
    for (int l = 0; l < 2; ++l) {
      int f = tid + l * 256;
      int kk = f >> 5;              // 0..15
      int nn = (f & 31) << 2;       // 0..124
      *(float4*)&Bs[kk][nn] =
          *(const float4*)(W1 + (size_t)(k0 + kk) * 1024 + col0 + nn);
    }
    __syncthreads();

#pragma unroll
    for (int k = 0; k < BK; ++k) {
      float a[8], b[8];
      *(float4*)&a[0] = *(const float4*)&As[k][ty * 8];
      *(float4*)&a[4] = *(const float4*)&As[k][ty * 8 + 4];
      *(float4*)&b[0] = *(const float4*)&Bs[k][tx * 8];
      *(float4*)&b[4] = *(const float4*)&Bs[k][tx * 8 + 4];
#pragma unroll
      for (int i = 0; i < 8; ++i)
#pragma unroll
        for (int j = 0; j < 8; ++j) acc[i][j] = fmaf(a[i], b[j], acc[i][j]);
    }
    __syncthreads();
  }

#pragma unroll
  for (int i = 0; i < 8; ++i) {
    int m = row0 + ty * 8 + i;
    float* dst = Hs + (size_t)m * 1024 + col0 + tx * 8;
    *(float4*)dst = *(float4*)&acc[i][0];
    *(float4*)(dst + 4) = *(float4*)&acc[i][4];
  }
}

// ---------------------------------------------------------------------------
// GEMM2 + fused epilogue:
// hc[65536,1024] = ent_table[cand_ids] @ W1[D:]   (K=256)
// h = relu(hc + Hs[row>>4] + b1); partial_score[row] += h . W2[tile]
// atomicAdd partial scores into score_ws[65536].
// ---------------------------------------------------------------------------
__global__ __launch_bounds__(256) void k_hc(const float* __restrict__ ent,
                                            const float* __restrict__ W1,
                                            const int* __restrict__ cand_ids,
                                            const float* __restrict__ Hs,
                                            const float* __restrict__ b1,
                                            const float* __restrict__ W2,
                                            float* __restrict__ score_ws) {
  const int tid = threadIdx.x;
  const int tx = tid & 15, ty = tid >> 4;
  const int row0 = blockIdx.y * BM;  // grid.y = 512
  const int col0 = blockIdx.x * BN;  // grid.x = 8

  __shared__ float As[BK][BM + PAD];
  __shared__ float Bs[BK][BN + PAD];
  __shared__ int rows_g[BM];
  __shared__ float red[BM][17];

  if (tid < BM) rows_g[tid] = cand_ids[row0 + tid];
  __syncthreads();

  float acc[8][8] = {};

  for (int k0 = 0; k0 < 256; k0 += BK) {
#pragma unroll
    for (int l = 0; l < 2; ++l) {
      int f = tid + l * 256;
      int r = f >> 2;
      int kk = (f & 3) << 2;
      const float4 v =
          *(const float4*)(ent + (size_t)rows_g[r] * 256 + k0 + kk);
      As[kk + 0][r] = v.x;
      As[kk + 1][r] = v.y;
      As[kk + 2][r] = v.z;
      As[kk + 3][r] = v.w;
    }
#pragma unroll
    for (int l = 0; l < 2; ++l) {
      int f = tid + l * 256;
      int kk = f >> 5;
      int nn = (f & 31) << 2;
      *(float4*)&Bs[kk][nn] =
          *(const float4*)(W1 + (size_t)(1024 + k0 + kk) * 1024 + col0 + nn);
    }
    __syncthreads();

#pragma unroll
    for (int k = 0; k < BK; ++k) {
      float a[8], b[8];
      *(float4*)&a[0] = *(const float4*)&As[k][ty * 8];
      *(float4*)&a[4] = *(const float4*)&As[k][ty * 8 + 4];
      *(float4*)&b[0] = *(const float4*)&Bs[k][tx * 8];
      *(float4*)&b[4] = *(const float4*)&Bs[k][tx * 8 + 4];
#pragma unroll
      for (int i = 0; i < 8; ++i)
#pragma unroll
        for (int j = 0; j < 8; ++j) acc[i][j] = fmaf(a[i], b[j], acc[i][j]);
    }
    __syncthreads();
  }

  // epilogue: rows ty*8..ty*8+7 all belong to one (b,s) pair (8 | 16 align)
  const int pair = (row0 + ty * 8) >> 4;
  float hsv[8], b1v[8], w2v[8];
  {
    const float* hp = Hs + (size_t)pair * 1024 + col0 + tx * 8;
    *(float4*)&hsv[0] = *(const float4*)hp;
    *(float4*)&hsv[4] = *(const float4*)(hp + 4);
    const float* bp = b1 + col0 + tx * 8;
    *(float4*)&b1v[0] = *(const float4*)bp;
    *(float4*)&b1v[4] = *(const float4*)(bp + 4);
    const float* wp = W2 + col0 + tx * 8;
    *(float4*)&w2v[0] = *(const float4*)wp;
    *(float4*)&w2v[4] = *(const float4*)(wp + 4);
  }
#pragma unroll
  for (int i = 0; i < 8; ++i) {
    float s = 0.f;
#pragma unroll
    for (int j = 0; j < 8; ++j) {
      float h = acc[i][j] + hsv[j] + b1v[j];
      h = fmaxf(h, 0.f);
      s = fmaf(h, w2v[j], s);
    }
    red[ty * 8 + i][tx] = s;
  }
  __syncthreads();
  if (tid < BM) {
    float s = 0.f;
#pragma unroll
    for (int x = 0; x < 16; ++x) s += red[tid][x];
    atomicAdd(&score_ws[row0 + tid], s);
  }
}

// ---------------------------------------------------------------------------
// Finalize: per (b,s) pair -> scores out (+b2), masked BCE loss, argmax preds.
// ---------------------------------------------------------------------------
__global__ __launch_bounds__(256) void k_final(const float* __restrict__ score_ws,
                                               const float* __restrict__ b2p,
                                               const float* __restrict__ targets_all,
                                               const int* __restrict__ linker,
                                               const int* __restrict__ len_all,
                                               float* __restrict__ out) {
  int p = blockIdx.x * 256 + threadIdx.x;  // [0, 4096)
  float b2 = b2p[0];
  int b = p >> 9;
  int i = linker[p];
  int len = len_all[(b << 12) + i];
  const float* tg = targets_all + ((((size_t)b << 12) + (size_t)i) << 4);

  float loss = 0.f;
  float best = -INFINITY;
  int bc = 0;
#pragma unroll
  for (int c = 0; c < 16; ++c) {
    float sc = score_ws[p * 16 + c] + b2;
    out[1 + p * 16 + c] = sc;
    float val;
    if (c < len) {
      float t = tg[c];
      loss += fmaxf(sc, 0.f) - sc * t + log1pf(expf(-fabsf(sc)));
      val = sc;
    } else {
      val = sc - 1e23f;  // matches reference: scores - (1-mask)*1e23
    }
    if (val > best) { best = val; bc = c; }  // strict > == first-max tiebreak
  }
  out[1 + 65536 + p] = (float)bc;

  // wave-64 reduction of loss, one atomic per wave
  for (int off = 32; off > 0; off >>= 1) loss += __shfl_down(loss, off, 64);
  if ((threadIdx.x & 63) == 0) atomicAdd(out, loss);
}

// ---------------------------------------------------------------------------
extern "C" void kernel_launch(void* const* d_in, const int* in_sizes, int n_in,
                              void* d_out, int out_size, void* d_ws,
                              size_t ws_size, hipStream_t stream) {
  const float* span    = (const float*)d_in[0];  // (8,4096,1024)
  const float* ent     = (const float*)d_in[1];  // (100000,256)
  const float* W1      = (const float*)d_in[2];  // (1280,1024)
  const float* b1      = (const float*)d_in[3];  // (1024)
  const float* W2      = (const float*)d_in[4];  // (1024)
  const float* b2      = (const float*)d_in[5];  // ()
  const float* targets = (const float*)d_in[6];  // (8,4096,16)
  const int* linker    = (const int*)d_in[7];    // (8,512)
  const int* cand_all  = (const int*)d_in[8];    // (8,4096,16)
  const int* len_all   = (const int*)d_in[9];    // (8,4096)
  float* out = (float*)d_out;

  float* Hs = (float*)d_ws;                      // 4096*1024 floats
  float* score_ws = Hs + (size_t)4096 * 1024;    // 65536 floats
  int* cand_ids = (int*)(score_ws + 65536);      // 65536 ints

  hipMemsetAsync(d_out, 0, sizeof(float), stream);          // loss accumulator
  hipMemsetAsync(score_ws, 0, 65536 * sizeof(float), stream);

  k_prep<<<dim3(256), dim3(256), 0, stream>>>(linker, cand_all, cand_ids);

  dim3 g1(8, 32);
  k_hs<<<g1, dim3(256), 0, stream>>>(span, W1, linker, Hs);

  dim3 g2(8, 512);
  k_hc<<<g2, dim3(256), 0, stream>>>(ent, W1, cand_ids, Hs, b1, W2, score_ws);

  k_final<<<dim3(16), dim3(256), 0, stream>>>(score_ws, b2, targets, linker,
                                              len_all, out);
}

// Round 2
// 440.189 us; speedup vs baseline: 1.7293x; 1.7293x over previous
//
#include <hip/hip_runtime.h>
#include <math.h>

// B=8, N=4096, S=512, C=16, D=1024, E=256, H=1024, V=100000
// d_out (float32): [0]=loss, [1..65536]=scores (8,512,16), [65537..69632]=preds

typedef short short8 __attribute__((ext_vector_type(8)));
typedef float f32x4 __attribute__((ext_vector_type(4)));

static __device__ inline unsigned short f2bf(float x) {
  unsigned u = __float_as_uint(x);
  unsigned r = (u + 0x7FFFu + ((u >> 16) & 1u)) >> 16;
  return (unsigned short)r;
}
static __device__ inline float bf2f(unsigned short b) {
  return __uint_as_float(((unsigned)b) << 16);
}

#define GLD_TO_LDS(gp, lp)                                          \
  __builtin_amdgcn_global_load_lds(                                 \
      (const __attribute__((address_space(1))) void*)(gp),          \
      (__attribute__((address_space(3))) void*)(lp), 16, 0, 0)

// ---------------------------------------------------------------------------
// Prep: candidate ids + span source rows.
// ---------------------------------------------------------------------------
__global__ __launch_bounds__(256) void k_prep2(const int* __restrict__ linker,
                                               const int* __restrict__ cand_all,
                                               int* __restrict__ cand_ids,
                                               int* __restrict__ span_rows) {
  int g = blockIdx.x * 256 + threadIdx.x;  // [0, 65536)
  int pair = g >> 4;
  int b = pair >> 9;
  int i = linker[pair];
  cand_ids[g] = cand_all[(((size_t)b << 12) + (size_t)i) * 16 + (g & 15)];
  if (g < 4096) span_rows[g] = ((g >> 9) << 12) + linker[g];
}

// ---------------------------------------------------------------------------
// Gather rows and split fp32 -> bf16 hi/lo.  LOG4: log2(rowlen/4).
// ---------------------------------------------------------------------------
template <int LOG4>
__global__ __launch_bounds__(256) void k_gsplit(const float* __restrict__ src,
                                                const int* __restrict__ rows,
                                                unsigned short* __restrict__ hi,
                                                unsigned short* __restrict__ lo) {
  int f = blockIdx.x * 256 + threadIdx.x;  // one float4
  int row = f >> LOG4;
  int c4 = f & ((1 << LOG4) - 1);
  const float4 v =
      *((const float4*)(src + ((size_t)rows[row] << (LOG4 + 2))) + c4);
  unsigned short h0 = f2bf(v.x), h1 = f2bf(v.y), h2 = f2bf(v.z), h3 = f2bf(v.w);
  unsigned short l0 = f2bf(v.x - bf2f(h0)), l1 = f2bf(v.y - bf2f(h1));
  unsigned short l2 = f2bf(v.z - bf2f(h2)), l3 = f2bf(v.w - bf2f(h3));
  *(ushort4*)(hi + ((size_t)f << 2)) = make_ushort4(h0, h1, h2, h3);
  *(ushort4*)(lo + ((size_t)f << 2)) = make_ushort4(l0, l1, l2, l3);
}

// ---------------------------------------------------------------------------
// W1 (1280x1024) -> transposed bf16 splits: W1sT[n][k<1024], W1eT[n][k-1024].
// ---------------------------------------------------------------------------
__global__ __launch_bounds__(256) void k_w1t(const float* __restrict__ W1,
                                             unsigned short* __restrict__ sThi,
                                             unsigned short* __restrict__ sTlo,
                                             unsigned short* __restrict__ eThi,
                                             unsigned short* __restrict__ eTlo) {
  __shared__ float t[32][33];
  int n0 = blockIdx.x * 32, k0 = blockIdx.y * 32;
  int rr = threadIdx.x >> 5, cc = threadIdx.x & 31;
#pragma unroll
  for (int i = 0; i < 4; ++i)
    t[rr + 8 * i][cc] = W1[(size_t)(k0 + rr + 8 * i) * 1024 + n0 + cc];
  __syncthreads();
#pragma unroll
  for (int i = 0; i < 4; ++i) {
    int nl = rr + 8 * i;
    float v = t[cc][nl];
    unsigned short h = f2bf(v);
    unsigned short l = f2bf(v - bf2f(h));
    int n = n0 + nl, k = k0 + cc;
    if (k0 < 1024) {
      sThi[(size_t)n * 1024 + k] = h;
      sTlo[(size_t)n * 1024 + k] = l;
    } else {
      eThi[(size_t)n * 256 + (k - 1024)] = h;
      eTlo[(size_t)n * 256 + (k - 1024)] = l;
    }
  }
}

// ---------------------------------------------------------------------------
// Split-2 bf16 MFMA GEMM, 128x128 tile, BK=32, 512 threads (2x4 wave grid).
// A[m][k] from Ahi/Alo [M][RL], B[k][n] from Bhi/Blo stored transposed [n][RL].
// MODE 0: Out[m*1024+n] = acc (write Hs fp32)
// MODE 1: fused relu(acc + HsIn[pair][n] + b1[n]) . W2 -> atomicAdd Out[m]
// ---------------------------------------------------------------------------
template <int KSTEPS, int RL, int MODE>
__global__ __launch_bounds__(512, 2) void k_gemm(
    const unsigned short* __restrict__ Ahi, const unsigned short* __restrict__ Alo,
    const unsigned short* __restrict__ Bhi, const unsigned short* __restrict__ Blo,
    const float* __restrict__ HsIn, const float* __restrict__ b1,
    const float* __restrict__ W2, float* __restrict__ Out) {
  const int tid = threadIdx.x;
  const int l = tid & 63;
  const int w = tid >> 6;       // 0..7
  const int wm = w >> 2;        // 0..1 (64 rows each)
  const int wn = w & 3;         // 0..3 (32 cols each)
  const int row0 = blockIdx.y * 128;
  const int col0 = blockIdx.x * 128;

  // 4 regions (A_hi, A_lo, B_hi, B_lo), each [128 rows][32 bf16], XOR-swizzled
  __shared__ unsigned short lds[4][128][32];

  f32x4 acc[4][2];
#pragma unroll
  for (int i = 0; i < 4; ++i)
#pragma unroll
    for (int j = 0; j < 2; ++j)
#pragma unroll
      for (int k = 0; k < 4; ++k) acc[i][j][k] = 0.f;

  // staging: thread tid stages chunk tid of each region (row=tid>>2, slot=tid&3)
  const int srow = tid >> 2;
  const int sc = tid & 3;
  const int swz = ((sc ^ ((srow >> 1) & 3)) << 3);  // element offset of chunk
  const size_t abase = (size_t)(row0 + srow) * RL + swz;
  const size_t bbase = (size_t)(col0 + srow) * RL + swz;
  unsigned short* const ldsw = &lds[0][0][0] + w * 512;  // wave-uniform

  for (int ks = 0; ks < KSTEPS; ++ks) {
    const int k0 = ks * 32;
    if (ks) __syncthreads();
    GLD_TO_LDS(Ahi + abase + k0, ldsw + 0 * 4096);
    GLD_TO_LDS(Alo + abase + k0, ldsw + 1 * 4096);
    GLD_TO_LDS(Bhi + bbase + k0, ldsw + 2 * 4096);
    GLD_TO_LDS(Blo + bbase + k0, ldsw + 3 * 4096);
    __syncthreads();

    short8 ah[4], al[4], bh[2], bl[2];
    const int kq = l >> 4;
    const unsigned short* lf = &lds[0][0][0];
#pragma unroll
    for (int it = 0; it < 4; ++it) {
      int r = wm * 64 + it * 16 + (l & 15);
      int off = r * 32 + ((kq ^ ((r >> 1) & 3)) << 3);
      ah[it] = *(const short8*)(lf + 0 * 4096 + off);
      al[it] = *(const short8*)(lf + 1 * 4096 + off);
    }
#pragma unroll
    for (int jt = 0; jt < 2; ++jt) {
      int r = wn * 32 + jt * 16 + (l & 15);
      int off = r * 32 + ((kq ^ ((r >> 1) & 3)) << 3);
      bh[jt] = *(const short8*)(lf + 2 * 4096 + off);
      bl[jt] = *(const short8*)(lf + 3 * 4096 + off);
    }
#pragma unroll
    for (int it = 0; it < 4; ++it)
#pragma unroll
      for (int jt = 0; jt < 2; ++jt) {
        acc[it][jt] = __builtin_amdgcn_mfma_f32_16x16x32_bf16(
            ah[it], bh[jt], acc[it][jt], 0, 0, 0);
        acc[it][jt] = __builtin_amdgcn_mfma_f32_16x16x32_bf16(
            ah[it], bl[jt], acc[it][jt], 0, 0, 0);
        acc[it][jt] = __builtin_amdgcn_mfma_f32_16x16x32_bf16(
            al[it], bh[jt], acc[it][jt], 0, 0, 0);
      }
  }

  if (MODE == 0) {
    // C/D layout: row=(l>>4)*4+reg, col=l&15
#pragma unroll
    for (int it = 0; it < 4; ++it) {
      int m = row0 + wm * 64 + it * 16 + (l >> 4) * 4;
#pragma unroll
      for (int jt = 0; jt < 2; ++jt) {
        int n = col0 + wn * 32 + jt * 16 + (l & 15);
#pragma unroll
        for (int rg = 0; rg < 4; ++rg)
          Out[(size_t)(m + rg) * 1024 + n] = acc[it][jt][rg];
      }
    }
  } else {
#pragma unroll
    for (int it = 0; it < 4; ++it) {
      int mbase = row0 + wm * 64 + it * 16;
      int pair = mbase >> 4;
      float s0 = 0.f, s1 = 0.f, s2 = 0.f, s3 = 0.f;
#pragma unroll
      for (int jt = 0; jt < 2; ++jt) {
        int n = col0 + wn * 32 + jt * 16 + (l & 15);
        float add = HsIn[(size_t)pair * 1024 + n] + b1[n];
        float w2v = W2[n];
        float h;
        h = fmaxf(acc[it][jt][0] + add, 0.f); s0 = fmaf(h, w2v, s0);
        h = fmaxf(acc[it][jt][1] + add, 0.f); s1 = fmaf(h, w2v, s1);
        h = fmaxf(acc[it][jt][2] + add, 0.f); s2 = fmaf(h, w2v, s2);
        h = fmaxf(acc[it][jt][3] + add, 0.f); s3 = fmaf(h, w2v, s3);
      }
#pragma unroll
      for (int off = 1; off < 16; off <<= 1) {
        s0 += __shfl_xor(s0, off, 64);
        s1 += __shfl_xor(s1, off, 64);
        s2 += __shfl_xor(s2, off, 64);
        s3 += __shfl_xor(s3, off, 64);
      }
      if ((l & 15) == 0) {
        int m = mbase + (l >> 4) * 4;
        atomicAdd(&Out[m + 0], s0);
        atomicAdd(&Out[m + 1], s1);
        atomicAdd(&Out[m + 2], s2);
        atomicAdd(&Out[m + 3], s3);
      }
    }
  }
}

// ---------------------------------------------------------------------------
// Finalize: scores (+b2), masked BCE loss, argmax predictions.
// ---------------------------------------------------------------------------
__global__ __launch_bounds__(256) void k_final(const float* __restrict__ score_ws,
                                               const float* __restrict__ b2p,
                                               const float* __restrict__ targets_all,
                                               const int* __restrict__ linker,
                                               const int* __restrict__ len_all,
                                               float* __restrict__ out) {
  int p = blockIdx.x * 256 + threadIdx.x;  // [0, 4096)
  float b2 = b2p[0];
  int b = p >> 9;
  int i = linker[p];
  int len = len_all[(b << 12) + i];
  const float* tg = targets_all + ((((size_t)b << 12) + (size_t)i) << 4);

  float loss = 0.f;
  float best = -INFINITY;
  int bc = 0;
#pragma unroll
  for (int c = 0; c < 16; ++c) {
    float sc = score_ws[p * 16 + c] + b2;
    out[1 + p * 16 + c] = sc;
    float val;
    if (c < len) {
      float t = tg[c];
      loss += fmaxf(sc, 0.f) - sc * t + log1pf(expf(-fabsf(sc)));
      val = sc;
    } else {
      val = sc - 1e23f;
    }
    if (val > best) { best = val; bc = c; }
  }
  out[1 + 65536 + p] = (float)bc;

  for (int off = 32; off > 0; off >>= 1) loss += __shfl_down(loss, off, 64);
  if ((threadIdx.x & 63) == 0) atomicAdd(out, loss);
}

// ===========================================================================
// Fallback fp32 path (round-1, proven) — used if ws_size is too small.
// ===========================================================================
#define BM 128
#define BN 128
#define BK 16
#define PAD 4

__global__ __launch_bounds__(256) void k_prep(const int* __restrict__ linker,
                                              const int* __restrict__ cand_all,
                                              int* __restrict__ cand_ids) {
  int g = blockIdx.x * 256 + threadIdx.x;
  int pair = g >> 4;
  int c = g & 15;
  int b = pair >> 9;
  int i = linker[pair];
  cand_ids[g] = cand_all[(((size_t)b << 12) + (size_t)i) * 16 + c];
}

__global__ __launch_bounds__(256) void k_hs(const float* __restrict__ span,
                                            const float* __restrict__ W1,
                                            const int* __restrict__ linker,
                                            float* __restrict__ Hs) {
  const int tid = threadIdx.x;
  const int tx = tid & 15, ty = tid >> 4;
  const int row0 = blockIdx.y * BM;
  const int col0 = blockIdx.x * BN;
  __shared__ float As[BK][BM + PAD];
  __shared__ float Bs[BK][BN + PAD];
  __shared__ int rows_g[BM];
  if (tid < BM) {
    int m = row0 + tid;
    int b = m >> 9;
    rows_g[tid] = (b << 12) + linker[m];
  }
  __syncthreads();
  float acc[8][8] = {};
  for (int k0 = 0; k0 < 1024; k0 += BK) {
#pragma unroll
    for (int ll = 0; ll < 2; ++ll) {
      int f = tid + ll * 256;
      int r = f >> 2;
      int kk = (f & 3) << 2;
      const float4 v = *(const float4*)(span + (size_t)rows_g[r] * 1024 + k0 + kk);
      As[kk + 0][r] = v.x; As[kk + 1][r] = v.y;
      As[kk + 2][r] = v.z; As[kk + 3][r] = v.w;
    }
#pragma unroll
    for (int ll = 0; ll < 2; ++ll) {
      int f = tid + ll * 256;
      int kk = f >> 5;
      int nn = (f & 31) << 2;
      *(float4*)&Bs[kk][nn] = *(const float4*)(W1 + (size_t)(k0 + kk) * 1024 + col0 + nn);
    }
    __syncthreads();
#pragma unroll
    for (int k = 0; k < BK; ++k) {
      float a[8], b[8];
      *(float4*)&a[0] = *(const float4*)&As[k][ty * 8];
      *(float4*)&a[4] = *(const float4*)&As[k][ty * 8 + 4];
      *(float4*)&b[0] = *(const float4*)&Bs[k][tx * 8];
      *(float4*)&b[4] = *(const float4*)&Bs[k][tx * 8 + 4];
#pragma unroll
      for (int i = 0; i < 8; ++i)
#pragma unroll
        for (int j = 0; j < 8; ++j) acc[i][j] = fmaf(a[i], b[j], acc[i][j]);
    }
    __syncthreads();
  }
#pragma unroll
  for (int i = 0; i < 8; ++i) {
    int m = row0 + ty * 8 + i;
    float* dst = Hs + (size_t)m * 1024 + col0 + tx * 8;
    *(float4*)dst = *(float4*)&acc[i][0];
    *(float4*)(dst + 4) = *(float4*)&acc[i][4];
  }
}

__global__ __launch_bounds__(256) void k_hc(const float* __restrict__ ent,
                                            const float* __restrict__ W1,
                                            const int* __restrict__ cand_ids,
                                            const float* __restrict__ Hs,
                                            const float* __restrict__ b1,
                                            const float* __restrict__ W2,
                                            float* __restrict__ score_ws) {
  const int tid = threadIdx.x;
  const int tx = tid & 15, ty = tid >> 4;
  const int row0 = blockIdx.y * BM;
  const int col0 = blockIdx.x * BN;
  __shared__ float As[BK][BM + PAD];
  __shared__ float Bs[BK][BN + PAD];
  __shared__ int rows_g[BM];
  __shared__ float red[BM][17];
  if (tid < BM) rows_g[tid] = cand_ids[row0 + tid];
  __syncthreads();
  float acc[8][8] = {};
  for (int k0 = 0; k0 < 256; k0 += BK) {
#pragma unroll
    for (int ll = 0; ll < 2; ++ll) {
      int f = tid + ll * 256;
      int r = f >> 2;
      int kk = (f & 3) << 2;
      const float4 v = *(const float4*)(ent + (size_t)rows_g[r] * 256 + k0 + kk);
      As[kk + 0][r] = v.x; As[kk + 1][r] = v.y;
      As[kk + 2][r] = v.z; As[kk + 3][r] = v.w;
    }
#pragma unroll
    for (int ll = 0; ll < 2; ++ll) {
      int f = tid + ll * 256;
      int kk = f >> 5;
      int nn = (f & 31) << 2;
      *(float4*)&Bs[kk][nn] =
          *(const float4*)(W1 + (size_t)(1024 + k0 + kk) * 1024 + col0 + nn);
    }
    __syncthreads();
#pragma unroll
    for (int k = 0; k < BK; ++k) {
      float a[8], b[8];
      *(float4*)&a[0] = *(const float4*)&As[k][ty * 8];
      *(float4*)&a[4] = *(const float4*)&As[k][ty * 8 + 4];
      *(float4*)&b[0] = *(const float4*)&Bs[k][tx * 8];
      *(float4*)&b[4] = *(const float4*)&Bs[k][tx * 8 + 4];
#pragma unroll
      for (int i = 0; i < 8; ++i)
#pragma unroll
        for (int j = 0; j < 8; ++j) acc[i][j] = fmaf(a[i], b[j], acc[i][j]);
    }
    __syncthreads();
  }
  const int pair = (row0 + ty * 8) >> 4;
  float hsv[8], b1v[8], w2v[8];
  {
    const float* hp = Hs + (size_t)pair * 1024 + col0 + tx * 8;
    *(float4*)&hsv[0] = *(const float4*)hp;
    *(float4*)&hsv[4] = *(const float4*)(hp + 4);
    const float* bp = b1 + col0 + tx * 8;
    *(float4*)&b1v[0] = *(const float4*)bp;
    *(float4*)&b1v[4] = *(const float4*)(bp + 4);
    const float* wp = W2 + col0 + tx * 8;
    *(float4*)&w2v[0] = *(const float4*)wp;
    *(float4*)&w2v[4] = *(const float4*)(wp + 4);
  }
#pragma unroll
  for (int i = 0; i < 8; ++i) {
    float s = 0.f;
#pragma unroll
    for (int j = 0; j < 8; ++j) {
      float h = acc[i][j] + hsv[j] + b1v[j];
      h = fmaxf(h, 0.f);
      s = fmaf(h, w2v[j], s);
    }
    red[ty * 8 + i][tx] = s;
  }
  __syncthreads();
  if (tid < BM) {
    float s = 0.f;
#pragma unroll
    for (int x = 0; x < 16; ++x) s += red[tid][x];
    atomicAdd(&score_ws[row0 + tid], s);
  }
}

// ===========================================================================
extern "C" void kernel_launch(void* const* d_in, const int* in_sizes, int n_in,
                              void* d_out, int out_size, void* d_ws,
                              size_t ws_size, hipStream_t stream) {
  const float* span    = (const float*)d_in[0];
  const float* ent     = (const float*)d_in[1];
  const float* W1      = (const float*)d_in[2];
  const float* b1      = (const float*)d_in[3];
  const float* W2      = (const float*)d_in[4];
  const float* b2      = (const float*)d_in[5];
  const float* targets = (const float*)d_in[6];
  const int* linker    = (const int*)d_in[7];
  const int* cand_all  = (const int*)d_in[8];
  const int* len_all   = (const int*)d_in[9];
  float* out = (float*)d_out;

  char* ws = (char*)d_ws;
  float* Hs       = (float*)(ws + 0);            // 16,777,216 B
  float* score_ws = (float*)(ws + 16777216);     //    262,144 B
  int* cand_ids   = (int*)(ws + 17039360);       //    262,144 B
  int* span_rows  = (int*)(ws + 17301504);       //     16,384 B
  unsigned short* A1h  = (unsigned short*)(ws + 17317888);   // 8,388,608
  unsigned short* A1l  = (unsigned short*)(ws + 25706496);   // 8,388,608
  unsigned short* A2h  = (unsigned short*)(ws + 34095104);   // 33,554,432
  unsigned short* A2l  = (unsigned short*)(ws + 67649536);   // 33,554,432
  unsigned short* sTh  = (unsigned short*)(ws + 101203968);  // 2,097,152
  unsigned short* sTl  = (unsigned short*)(ws + 103301120);  // 2,097,152
  unsigned short* eTh  = (unsigned short*)(ws + 105398272);  //   524,288
  unsigned short* eTl  = (unsigned short*)(ws + 105922560);  //   524,288
  const size_t NEED_MFMA = 106446848;

  hipMemsetAsync(d_out, 0, sizeof(float), stream);
  hipMemsetAsync(score_ws, 0, 65536 * sizeof(float), stream);

  if (ws_size >= NEED_MFMA) {
    k_prep2<<<dim3(256), dim3(256), 0, stream>>>(linker, cand_all, cand_ids,
                                                 span_rows);
    k_gsplit<6><<<dim3(16384), dim3(256), 0, stream>>>(ent, cand_ids, A2h, A2l);
    k_gsplit<8><<<dim3(4096), dim3(256), 0, stream>>>(span, span_rows, A1h, A1l);
    k_w1t<<<dim3(32, 40), dim3(256), 0, stream>>>(W1, sTh, sTl, eTh, eTl);
    k_gemm<32, 1024, 0><<<dim3(8, 32), dim3(512), 0, stream>>>(
        A1h, A1l, sTh, sTl, nullptr, nullptr, nullptr, Hs);
    k_gemm<8, 256, 1><<<dim3(8, 512), dim3(512), 0, stream>>>(
        A2h, A2l, eTh, eTl, Hs, b1, W2, score_ws);
  } else {
    k_prep<<<dim3(256), dim3(256), 0, stream>>>(linker, cand_all, cand_ids);
    dim3 g1(8, 32);
    k_hs<<<g1, dim3(256), 0, stream>>>(span, W1, linker, Hs);
    dim3 g2(8, 512);
    k_hc<<<g2, dim3(256), 0, stream>>>(ent, W1, cand_ids, Hs, b1, W2, score_ws);
  }

  k_final<<<dim3(16), dim3(256), 0, stream>>>(score_ws, b2, targets, linker,
                                              len_all, out);
}